// Round 15
// baseline (277.604 us; speedup 1.0000x reference)
//
#include <hip/hip_runtime.h>
#include <math.h>

#define N_NODES 50000
#define N_EDGES 1600000
#define HDIM 128
#define NGRAPH 512
#define NCLS 10

#define NSLICE 256
#define EDGES_PER_SLICE (N_EDGES / NSLICE)   // 6250
#define BSH 7                                 // bucket = node >> 7 (128 nodes/bucket)
#define NBUCK 391                             // ceil(N_NODES / 128)
#define NHALF (N_NODES / 2)                   // 25000: L/H source split for L2 residency

typedef __attribute__((ext_vector_type(8))) short short8v;
typedef __attribute__((ext_vector_type(4))) float float4v;
typedef __attribute__((ext_vector_type(2))) float float2v;

// bf16 helpers
__device__ inline float blo(unsigned int v) { return __uint_as_float(v << 16); }
__device__ inline float bhi(unsigned int v) { return __uint_as_float(v & 0xffff0000u); }
__device__ inline float b2f(unsigned short u) { return __uint_as_float(((unsigned)u) << 16); }
__device__ inline unsigned short f2b(float f) {
  unsigned int u = __float_as_uint(f);
  unsigned int r = u + 0x7fffu + ((u >> 16) & 1u);   // RNE
  return (unsigned short)(r >> 16);
}
// fp8 e4m3 (OCP) hardware converts
__device__ inline unsigned char f2fp8(float f) {
  return (unsigned char)(__builtin_amdgcn_cvt_pk_fp8_f32(f, 0.f, 0, false) & 0xFF);
}
__device__ inline float2v fp8x2lo(unsigned int u) {
  return __builtin_amdgcn_cvt_pk_f32_fp8(u, false);   // bytes 0,1
}
__device__ inline float2v fp8x2hi(unsigned int u) {
  return __builtin_amdgcn_cvt_pk_f32_fp8(u, true);    // bytes 2,3
}

// ---------------- fp32 -> bf16 cast ----------------
__global__ __launch_bounds__(256) void cast4_k(const float* __restrict__ in, unsigned short* __restrict__ out, int n4) {
  int i = blockIdx.x * 256 + threadIdx.x;
  if (i < n4) {
    float4 v = ((const float4*)in)[i];
    ushort4 o;
    o.x = f2b(v.x); o.y = f2b(v.y); o.z = f2b(v.z); o.w = f2b(v.w);
    ((ushort4*)out)[i] = o;
  }
}

// all 4 layer weights in one launch (4 x 16384 fp32, 4 elems/thread)
__global__ __launch_bounds__(256) void castw_k(const float* __restrict__ w0, const float* __restrict__ w1,
                                               const float* __restrict__ w2, const float* __restrict__ w3,
                                               unsigned short* __restrict__ o0, unsigned short* __restrict__ o1,
                                               unsigned short* __restrict__ o2, unsigned short* __restrict__ o3) {
  int i = blockIdx.x * 256 + threadIdx.x;         // 0 .. 16383
  int l = i >> 12, j = i & 4095;                  // 4096 float4 per weight
  const float* in = (l == 0) ? w0 : (l == 1) ? w1 : (l == 2) ? w2 : w3;
  unsigned short* out = (l == 0) ? o0 : (l == 1) ? o1 : (l == 2) ? o2 : o3;
  float4 v = ((const float4*)in)[j];
  ushort4 o;
  o.x = f2b(v.x); o.y = f2b(v.y); o.z = f2b(v.z); o.w = f2b(v.w);
  ((ushort4*)out)[j] = o;
}

// ---------------- phase A1: per-slice coarse-bucket histogram ----------------
__global__ __launch_bounds__(256) void countA_k(const int* __restrict__ ei, int* __restrict__ partialB) {
  __shared__ int cnt[NBUCK];
  int s = blockIdx.x, t = threadIdx.x;
  for (int i = t; i < NBUCK; i += 256) cnt[i] = 0;
  __syncthreads();
  int base = s * EDGES_PER_SLICE;
  for (int i = t; i < EDGES_PER_SLICE; i += 256) {
    int c = ei[N_EDGES + base + i];
    atomicAdd(&cnt[c >> BSH], 1);
  }
  __syncthreads();
  for (int i = t; i < NBUCK; i += 256) partialB[s * NBUCK + i] = cnt[i];
}

// ---------------- phase A2a: per-bucket exclusive prefix over slices ----------------
__global__ __launch_bounds__(256) void prefixA1_k(int* __restrict__ partialB, int* __restrict__ boff) {
  int b = blockIdx.x * 256 + threadIdx.x;
  if (b >= NBUCK) return;
  int acc = 0;
  for (int s = 0; s < NSLICE; ++s) {
    int v = partialB[s * NBUCK + b];
    partialB[s * NBUCK + b] = acc;
    acc += v;
  }
  boff[b] = acc;
}

// ---------------- phase A2b: exclusive scan of bucket totals (1 block) ----------------
__global__ __launch_bounds__(512) void prefixA2_k(int* __restrict__ boff) {
  __shared__ int sd[512];
  int t = threadIdx.x;
  int my = (t < NBUCK) ? boff[t] : 0;
  sd[t] = my;
  __syncthreads();
  for (int d = 1; d < 512; d <<= 1) {
    int v = (t >= d) ? sd[t - d] : 0;
    __syncthreads();
    sd[t] += v;
    __syncthreads();
  }
  if (t < NBUCK) boff[t] = sd[t] - my;
  if (t == 511) boff[NBUCK] = sd[511];
}

// ---------------- phase A3: scatter edges into coarse buckets (packed 8B) ----------------
// record: w(32) << 32 | r(16) << 7 | c_local(7)
__global__ __launch_bounds__(256) void bucketA_k(const int* __restrict__ ei, const float* __restrict__ ew,
                                                 const int* __restrict__ partialB, const int* __restrict__ boff,
                                                 unsigned long long* __restrict__ bucketed) {
  __shared__ int rnk[NBUCK];
  __shared__ int sbase[NBUCK];
  int s = blockIdx.x, t = threadIdx.x;
  for (int i = t; i < NBUCK; i += 256) { rnk[i] = 0; sbase[i] = boff[i] + partialB[s * NBUCK + i]; }
  __syncthreads();
  int base = s * EDGES_PER_SLICE;
  for (int i = t; i < EDGES_PER_SLICE; i += 256) {
    int c = ei[N_EDGES + base + i];
    int r = ei[base + i];
    float w = ew[base + i];
    int bk = c >> BSH;
    int rank = atomicAdd(&rnk[bk], 1);
    unsigned long long v = ((unsigned long long)__float_as_uint(w) << 32)
                         | ((unsigned long long)(unsigned)r << BSH)
                         | (unsigned long long)(c & 127);
    bucketed[(size_t)sbase[bk] + rank] = v;
  }
}

// ---------------- phase B: per-bucket degree + CSR build, L/H split per node ----------------
// cpack = bf16(w)<<16 | r ; per node: [off, offH) sources r<NHALF, [offH, off+1) r>=NHALF
__global__ __launch_bounds__(256) void csrB_k(const unsigned long long* __restrict__ bucketed,
                                              const int* __restrict__ boff,
                                              int* __restrict__ off, int* __restrict__ offH,
                                              float* __restrict__ dinv,
                                              unsigned int* __restrict__ cpack) {
  __shared__ int cntL[128];
  __shared__ int cntH[128];
  __shared__ float wsum[128];
  __shared__ int sc[128];
  __shared__ int rnkL[128];
  __shared__ int rnkH[128];
  int b = blockIdx.x, t = threadIdx.x;
  if (t < 128) { cntL[t] = 0; cntH[t] = 0; rnkL[t] = 0; rnkH[t] = 0; wsum[t] = 1.0f; }  // self-loop w
  __syncthreads();
  int s = boff[b], e = boff[b + 1];
  for (int i = s + t; i < e; i += 256) {
    unsigned long long v = bucketed[i];
    int cl = (int)(v & 127);
    int r = (int)((v >> BSH) & 0xFFFF);
    if (r < NHALF) atomicAdd(&cntL[cl], 1); else atomicAdd(&cntH[cl], 1);
    atomicAdd(&wsum[cl], __uint_as_float((unsigned)(v >> 32)));
  }
  __syncthreads();
  if (t < 128) sc[t] = cntL[t] + cntH[t];
  __syncthreads();
  for (int d = 1; d < 128; d <<= 1) {
    int v = (t < 128 && t >= d) ? sc[t - d] : 0;
    __syncthreads();
    if (t < 128) sc[t] += v;
    __syncthreads();
  }
  int node = b * 128 + t;
  if (t < 128 && node < N_NODES) {
    int excl = sc[t] - (cntL[t] + cntH[t]);
    off[node] = s + excl;
    offH[node] = s + excl + cntL[t];
    dinv[node] = rsqrtf(wsum[t]);
  }
  __syncthreads();
  for (int i = s + t; i < e; i += 256) {
    unsigned long long v = bucketed[i];
    int cl = (int)(v & 127);
    int r = (int)((v >> BSH) & 0xFFFF);
    float w = __uint_as_float((unsigned)(v >> 32));
    int excl = sc[cl] - (cntL[cl] + cntH[cl]);
    int pos;
    if (r < NHALF) pos = s + excl + atomicAdd(&rnkL[cl], 1);
    else           pos = s + excl + cntL[cl] + atomicAdd(&rnkH[cl], 1);
    cpack[pos] = ((unsigned int)f2b(w) << 16) | (unsigned int)r;
  }
  if (b == 0 && t == 0) off[N_NODES] = N_EDGES;
}

// ---------------- MFMA bf16 GEMM, epilogue: fp8(dinv[row] * acc) ----------------
__global__ __launch_bounds__(256) void gemm_mfma_k(const unsigned short* __restrict__ A,
                                                   const unsigned short* __restrict__ W16,
                                                   const float* __restrict__ dinv,
                                                   unsigned char* __restrict__ Out8) {
  __shared__ unsigned short Wl[128 * 128];
  int t = threadIdx.x;
  for (int idx = t; idx < 2048; idx += 256) {
    int n = idx >> 4, G = idx & 15;
    short8v v = *(const short8v*)(W16 + n * 128 + G * 8);
    int Gs = G ^ (n & 15);
    *(short8v*)(&Wl[n * 128 + Gs * 8]) = v;
  }
  __syncthreads();

  int wave = t >> 6, lane = t & 63;
  int l15 = lane & 15, l4 = lane >> 4;
  int rbase = blockIdx.x * 128 + wave * 32;

  float4v acc[2][8];
#pragma unroll
  for (int m = 0; m < 2; ++m)
#pragma unroll
    for (int f = 0; f < 8; ++f) acc[m][f] = (float4v){0.f, 0.f, 0.f, 0.f};

  int r0 = rbase + l15;        if (r0 >= N_NODES) r0 = N_NODES - 1;
  int r1 = rbase + 16 + l15;   if (r1 >= N_NODES) r1 = N_NODES - 1;

#pragma unroll
  for (int s = 0; s < 4; ++s) {
    int kk = s * 32 + l4 * 8;
    short8v a0 = *(const short8v*)(A + (size_t)r0 * 128 + kk);
    short8v a1 = *(const short8v*)(A + (size_t)r1 * 128 + kk);
#pragma unroll
    for (int f = 0; f < 8; ++f) {
      int n = f * 16 + l15;
      int G = s * 4 + l4;
      int Gs = G ^ (n & 15);
      short8v bfr = *(const short8v*)(&Wl[n * 128 + Gs * 8]);
      acc[0][f] = __builtin_amdgcn_mfma_f32_16x16x32_bf16(a0, bfr, acc[0][f], 0, 0, 0);
      acc[1][f] = __builtin_amdgcn_mfma_f32_16x16x32_bf16(a1, bfr, acc[1][f], 0, 0, 0);
    }
  }

#pragma unroll
  for (int m = 0; m < 2; ++m) {
    int rb = rbase + m * 16 + l4 * 4;
#pragma unroll
    for (int r = 0; r < 4; ++r) {
      int row = rb + r;
      if (row < N_NODES) {
        float ds = dinv[row];
        unsigned char* orow = Out8 + (size_t)row * 128 + l15;
#pragma unroll
        for (int f = 0; f < 8; ++f) orow[f * 16] = f2fp8(acc[m][f][r] * ds);
      }
    }
  }
}

// ---------------- aggregate: out[c] = elu(dinv_c*(h8[c] + sum w*h8[r]) + b) ----------------
// 16 lanes per node (8 fp8 features per lane via u64 gathers), 4 nodes per wave,
// 16 nodes per block. Two source-range passes (r<NHALF then >=NHALF): each pass's
// gather working set is 3.2MB < 4MB per-XCD L2 -> gathers mostly L2-hit.
__global__ __launch_bounds__(256) void aggregate_k(const unsigned char* __restrict__ h8,
                                                   const float* __restrict__ dinv,
                                                   const int* __restrict__ off,
                                                   const int* __restrict__ offH,
                                                   const unsigned int* __restrict__ cpack,
                                                   const float* __restrict__ bias,
                                                   unsigned short* __restrict__ hout) {
  int c = blockIdx.x * 16 + (threadIdx.x >> 4);
  if (c >= N_NODES) return;
  int fl = threadIdx.x & 15;            // feature lane: features 8fl..8fl+7
  const uint2* h8q = (const uint2*)h8;  // 16 uint2 per row
  uint2 sv = h8q[((size_t)c << 4) + fl];
  float2v s0 = fp8x2lo(sv.x), s1 = fp8x2hi(sv.x), s2 = fp8x2lo(sv.y), s3 = fp8x2hi(sv.y);
  float a0 = s0.x, a1 = s0.y, a2 = s1.x, a3 = s1.y;
  float a4 = s2.x, a5 = s2.y, a6 = s3.x, a7 = s3.y;
  int s = off[c], m = offH[c], e = off[c + 1];
#define AGG_EDGE(G, W) { \
    float2v q0 = fp8x2lo(G.x), q1 = fp8x2hi(G.x), q2 = fp8x2lo(G.y), q3 = fp8x2hi(G.y); \
    a0 += W * q0.x; a1 += W * q0.y; a2 += W * q1.x; a3 += W * q1.y; \
    a4 += W * q2.x; a5 += W * q2.y; a6 += W * q3.x; a7 += W * q3.y; }
  for (int rge = 0; rge < 2; ++rge) {
    int k = rge ? m : s;
    int ke = rge ? e : m;
    for (; k + 8 <= ke; k += 8) {
      unsigned int p0 = cpack[k],   p1 = cpack[k+1], p2 = cpack[k+2], p3 = cpack[k+3];
      unsigned int p4 = cpack[k+4], p5 = cpack[k+5], p6 = cpack[k+6], p7 = cpack[k+7];
      uint2 g0 = h8q[((size_t)(p0 & 0xFFFF) << 4) + fl];
      uint2 g1 = h8q[((size_t)(p1 & 0xFFFF) << 4) + fl];
      uint2 g2 = h8q[((size_t)(p2 & 0xFFFF) << 4) + fl];
      uint2 g3 = h8q[((size_t)(p3 & 0xFFFF) << 4) + fl];
      uint2 g4 = h8q[((size_t)(p4 & 0xFFFF) << 4) + fl];
      uint2 g5 = h8q[((size_t)(p5 & 0xFFFF) << 4) + fl];
      uint2 g6 = h8q[((size_t)(p6 & 0xFFFF) << 4) + fl];
      uint2 g7 = h8q[((size_t)(p7 & 0xFFFF) << 4) + fl];
      float w0 = bhi(p0), w1 = bhi(p1), w2 = bhi(p2), w3 = bhi(p3);
      float w4 = bhi(p4), w5 = bhi(p5), w6 = bhi(p6), w7 = bhi(p7);
      AGG_EDGE(g0, w0) AGG_EDGE(g1, w1) AGG_EDGE(g2, w2) AGG_EDGE(g3, w3)
      AGG_EDGE(g4, w4) AGG_EDGE(g5, w5) AGG_EDGE(g6, w6) AGG_EDGE(g7, w7)
    }
    for (; k < ke; ++k) {
      unsigned int p = cpack[k];
      uint2 g = h8q[((size_t)(p & 0xFFFF) << 4) + fl];
      float w = bhi(p);
      AGG_EDGE(g, w)
    }
  }
#undef AGG_EDGE
  float dc = dinv[c];
  int col = fl * 8;
  float4 b0 = *(const float4*)(bias + col);
  float4 b1 = *(const float4*)(bias + col + 4);
  a0 = dc * a0 + b0.x;  a1 = dc * a1 + b0.y;  a2 = dc * a2 + b0.z;  a3 = dc * a3 + b0.w;
  a4 = dc * a4 + b1.x;  a5 = dc * a5 + b1.y;  a6 = dc * a6 + b1.z;  a7 = dc * a7 + b1.w;
  a0 = a0 > 0.f ? a0 : expm1f(a0);
  a1 = a1 > 0.f ? a1 : expm1f(a1);
  a2 = a2 > 0.f ? a2 : expm1f(a2);
  a3 = a3 > 0.f ? a3 : expm1f(a3);
  a4 = a4 > 0.f ? a4 : expm1f(a4);
  a5 = a5 > 0.f ? a5 : expm1f(a5);
  a6 = a6 > 0.f ? a6 : expm1f(a6);
  a7 = a7 > 0.f ? a7 : expm1f(a7);
  short8v o;
  o[0] = (short)f2b(a0); o[1] = (short)f2b(a1); o[2] = (short)f2b(a2); o[3] = (short)f2b(a3);
  o[4] = (short)f2b(a4); o[5] = (short)f2b(a5); o[6] = (short)f2b(a6); o[7] = (short)f2b(a7);
  *(short8v*)(hout + (size_t)c * 128 + col) = o;
}

// ---------------- fused mean-pool + head: 512 thr = 8 node-groups x 64 lanes ----------------
__global__ __launch_bounds__(512) void poolhead_k(const unsigned short* __restrict__ h,
                                                  const int* __restrict__ batch,
                                                  const float* __restrict__ fc1w, const float* __restrict__ fc1b,
                                                  const float* __restrict__ fc2w, const float* __restrict__ fc2b,
                                                  float* __restrict__ out) {
  __shared__ float part[8][HDIM];
  __shared__ float ps[HDIM];
  __shared__ float z1[HDIM];
  __shared__ float z2[NCLS];
  int g = blockIdx.x, t = threadIdx.x;
  int fl = t & 63;            // u32 word: features 2fl, 2fl+1
  int grp = t >> 6;           // 0..7
  int lo = 0, hi = N_NODES;
  while (lo < hi) { int mid = (lo + hi) >> 1; if (batch[mid] < g) lo = mid + 1; else hi = mid; }
  int gs = lo;
  hi = N_NODES;
  while (lo < hi) { int mid = (lo + hi) >> 1; if (batch[mid] < g + 1) lo = mid + 1; else hi = mid; }
  int ge = lo;
  const unsigned int* hw = (const unsigned int*)h;   // 64 u32 per row
  float a0 = 0.f, a1 = 0.f;
  for (int n = gs + grp; n < ge; n += 8) {
    unsigned int v = hw[((size_t)n << 6) + fl];
    a0 += blo(v); a1 += bhi(v);
  }
  part[grp][fl * 2] = a0;
  part[grp][fl * 2 + 1] = a1;
  __syncthreads();
  if (t < HDIM) {
    float s = 0.f;
#pragma unroll
    for (int q = 0; q < 8; ++q) s += part[q][t];
    ps[t] = s / (float)max(ge - gs, 1);
  }
  __syncthreads();
  if (t < HDIM) {
    float acc = fc1b[t];
    for (int i = 0; i < HDIM; ++i) acc += ps[i] * fc1w[t * HDIM + i];
    z1[t] = (acc > 0.f) ? acc : expm1f(acc);
  }
  __syncthreads();
  if (t < NCLS) {
    float a2 = fc2b[t];
    for (int i = 0; i < HDIM; ++i) a2 += z1[i] * fc2w[t * HDIM + i];
    z2[t] = a2;
  }
  __syncthreads();
  if (t == 0) {
    float m = -1e30f;
    for (int i = 0; i < NCLS; ++i) m = fmaxf(m, z2[i]);
    float s2 = 0.f;
    for (int i = 0; i < NCLS; ++i) s2 += expf(z2[i] - m);
    float l = logf(s2);
    for (int i = 0; i < NCLS; ++i) out[g * NCLS + i] = z2[i] - m - l;
  }
}

// ---------------- launch ----------------
static inline size_t align256(size_t x) { return (x + 255) & ~(size_t)255; }

extern "C" void kernel_launch(void* const* d_in, const int* in_sizes, int n_in,
                              void* d_out, int out_size, void* d_ws, size_t ws_size,
                              hipStream_t stream) {
  const float* x     = (const float*)d_in[0];
  const int*   ei    = (const int*)d_in[1];
  const float* ew    = (const float*)d_in[2];
  const int*   batch = (const int*)d_in[3];
  const float* Wl[4] = { (const float*)d_in[4], (const float*)d_in[6], (const float*)d_in[8], (const float*)d_in[10] };
  const float* bl[4] = { (const float*)d_in[5], (const float*)d_in[7], (const float*)d_in[9], (const float*)d_in[11] };
  const float* fc1w = (const float*)d_in[12];
  const float* fc1b = (const float*)d_in[13];
  const float* fc2w = (const float*)d_in[14];
  const float* fc2b = (const float*)d_in[15];
  float* out = (float*)d_out;

  char* ws = (char*)d_ws;
  size_t o = 0;
  unsigned short* x16 = (unsigned short*)(ws + o); o = align256(o + (size_t)N_NODES * HDIM * 2);
  unsigned short* h16 = (unsigned short*)(ws + o); o = align256(o + (size_t)N_NODES * HDIM * 2);
  // h8 (6.4MB) aliases bucketed (12.8MB): bucketed dead after csrB_k; h8 first
  // written by gemm_mfma_k (launched after csrB_k).
  unsigned char* h8 = (unsigned char*)(ws + o);
  unsigned long long* bucketed = (unsigned long long*)(ws + o);
  o = align256(o + (size_t)N_EDGES * 8);
  unsigned short* w16[4];
  for (int l = 0; l < 4; ++l) { w16[l] = (unsigned short*)(ws + o); o = align256(o + (size_t)HDIM * HDIM * 2); }
  unsigned int* cpack = (unsigned int*)(ws + o); o = align256(o + (size_t)N_EDGES * 4);
  int*   partialB = (int*)(ws + o);   o = align256(o + (size_t)NSLICE * NBUCK * 4);
  int*   boff     = (int*)(ws + o);   o = align256(o + (size_t)(NBUCK + 1) * 4);
  float* dinv  = (float*)(ws + o); o = align256(o + (size_t)N_NODES * 4);
  int*   off   = (int*)  (ws + o); o = align256(o + (size_t)(N_NODES + 1) * 4);
  int*   offH  = (int*)  (ws + o); o = align256(o + (size_t)(N_NODES + 1) * 4);

  cast4_k<<<(N_NODES * HDIM / 4 + 255) / 256, 256, 0, stream>>>(x, x16, N_NODES * HDIM / 4);
  castw_k<<<64, 256, 0, stream>>>(Wl[0], Wl[1], Wl[2], Wl[3], w16[0], w16[1], w16[2], w16[3]);

  countA_k<<<NSLICE, 256, 0, stream>>>(ei, partialB);
  prefixA1_k<<<(NBUCK + 255) / 256, 256, 0, stream>>>(partialB, boff);
  prefixA2_k<<<1, 512, 0, stream>>>(boff);
  bucketA_k<<<NSLICE, 256, 0, stream>>>(ei, ew, partialB, boff, bucketed);
  csrB_k<<<NBUCK, 256, 0, stream>>>(bucketed, boff, off, offH, dinv, cpack);

  const unsigned short* hin = x16;
  for (int l = 0; l < 4; ++l) {
    gemm_mfma_k<<<(N_NODES + 127) / 128, 256, 0, stream>>>(hin, w16[l], dinv, h8);
    aggregate_k<<<(N_NODES + 15) / 16, 256, 0, stream>>>(h8, dinv, off, offH, cpack, bl[l], h16);
    hin = h16;
  }

  poolhead_k<<<NGRAPH, 512, 0, stream>>>(h16, batch, fc1w, fc1b, fc2w, fc2b, out);
}

// Round 16
// 258.812 us; speedup vs baseline: 1.0726x; 1.0726x over previous
//
#include <hip/hip_runtime.h>
#include <math.h>

#define N_NODES 50000
#define N_EDGES 1600000
#define HDIM 128
#define NGRAPH 512
#define NCLS 10

#define NSLICE 256
#define EDGES_PER_SLICE (N_EDGES / NSLICE)   // 6250
#define BSH 7                                 // bucket = node >> 7 (128 nodes/bucket)
#define NBUCK 391                             // ceil(N_NODES / 128)

typedef __attribute__((ext_vector_type(8))) short short8v;
typedef __attribute__((ext_vector_type(4))) float float4v;
typedef __attribute__((ext_vector_type(2))) float float2v;

// bf16 helpers
__device__ inline float blo(unsigned int v) { return __uint_as_float(v << 16); }
__device__ inline float bhi(unsigned int v) { return __uint_as_float(v & 0xffff0000u); }
__device__ inline float b2f(unsigned short u) { return __uint_as_float(((unsigned)u) << 16); }
__device__ inline unsigned short f2b(float f) {
  unsigned int u = __float_as_uint(f);
  unsigned int r = u + 0x7fffu + ((u >> 16) & 1u);   // RNE
  return (unsigned short)(r >> 16);
}
// fp8 e4m3 (OCP) hardware converts
__device__ inline unsigned char f2fp8(float f) {
  return (unsigned char)(__builtin_amdgcn_cvt_pk_fp8_f32(f, 0.f, 0, false) & 0xFF);
}
__device__ inline float2v fp8x2lo(unsigned int u) {
  return __builtin_amdgcn_cvt_pk_f32_fp8(u, false);   // bytes 0,1
}
__device__ inline float2v fp8x2hi(unsigned int u) {
  return __builtin_amdgcn_cvt_pk_f32_fp8(u, true);    // bytes 2,3
}

// ---------------- fp32 -> bf16 cast ----------------
__global__ __launch_bounds__(256) void cast4_k(const float* __restrict__ in, unsigned short* __restrict__ out, int n4) {
  int i = blockIdx.x * 256 + threadIdx.x;
  if (i < n4) {
    float4 v = ((const float4*)in)[i];
    ushort4 o;
    o.x = f2b(v.x); o.y = f2b(v.y); o.z = f2b(v.z); o.w = f2b(v.w);
    ((ushort4*)out)[i] = o;
  }
}

// all 4 layer weights in one launch (4 x 16384 fp32, 4 elems/thread)
__global__ __launch_bounds__(256) void castw_k(const float* __restrict__ w0, const float* __restrict__ w1,
                                               const float* __restrict__ w2, const float* __restrict__ w3,
                                               unsigned short* __restrict__ o0, unsigned short* __restrict__ o1,
                                               unsigned short* __restrict__ o2, unsigned short* __restrict__ o3) {
  int i = blockIdx.x * 256 + threadIdx.x;         // 0 .. 16383
  int l = i >> 12, j = i & 4095;                  // 4096 float4 per weight
  const float* in = (l == 0) ? w0 : (l == 1) ? w1 : (l == 2) ? w2 : w3;
  unsigned short* out = (l == 0) ? o0 : (l == 1) ? o1 : (l == 2) ? o2 : o3;
  float4 v = ((const float4*)in)[j];
  ushort4 o;
  o.x = f2b(v.x); o.y = f2b(v.y); o.z = f2b(v.z); o.w = f2b(v.w);
  ((ushort4*)out)[j] = o;
}

// ---------------- phase A1: per-slice coarse-bucket histogram ----------------
__global__ __launch_bounds__(256) void countA_k(const int* __restrict__ ei, int* __restrict__ partialB) {
  __shared__ int cnt[NBUCK];
  int s = blockIdx.x, t = threadIdx.x;
  for (int i = t; i < NBUCK; i += 256) cnt[i] = 0;
  __syncthreads();
  int base = s * EDGES_PER_SLICE;
  for (int i = t; i < EDGES_PER_SLICE; i += 256) {
    int c = ei[N_EDGES + base + i];
    atomicAdd(&cnt[c >> BSH], 1);
  }
  __syncthreads();
  for (int i = t; i < NBUCK; i += 256) partialB[s * NBUCK + i] = cnt[i];
}

// ---------------- phase A2a: per-bucket exclusive prefix over slices ----------------
__global__ __launch_bounds__(256) void prefixA1_k(int* __restrict__ partialB, int* __restrict__ boff) {
  int b = blockIdx.x * 256 + threadIdx.x;
  if (b >= NBUCK) return;
  int acc = 0;
  for (int s = 0; s < NSLICE; ++s) {
    int v = partialB[s * NBUCK + b];
    partialB[s * NBUCK + b] = acc;
    acc += v;
  }
  boff[b] = acc;
}

// ---------------- phase A2b: exclusive scan of bucket totals (1 block) ----------------
__global__ __launch_bounds__(512) void prefixA2_k(int* __restrict__ boff) {
  __shared__ int sd[512];
  int t = threadIdx.x;
  int my = (t < NBUCK) ? boff[t] : 0;
  sd[t] = my;
  __syncthreads();
  for (int d = 1; d < 512; d <<= 1) {
    int v = (t >= d) ? sd[t - d] : 0;
    __syncthreads();
    sd[t] += v;
    __syncthreads();
  }
  if (t < NBUCK) boff[t] = sd[t] - my;
  if (t == 511) boff[NBUCK] = sd[511];
}

// ---------------- phase A3: scatter edges into coarse buckets (packed 8B) ----------------
// record: w(32) << 32 | r(16) << 7 | c_local(7)
__global__ __launch_bounds__(256) void bucketA_k(const int* __restrict__ ei, const float* __restrict__ ew,
                                                 const int* __restrict__ partialB, const int* __restrict__ boff,
                                                 unsigned long long* __restrict__ bucketed) {
  __shared__ int rnk[NBUCK];
  __shared__ int sbase[NBUCK];
  int s = blockIdx.x, t = threadIdx.x;
  for (int i = t; i < NBUCK; i += 256) { rnk[i] = 0; sbase[i] = boff[i] + partialB[s * NBUCK + i]; }
  __syncthreads();
  int base = s * EDGES_PER_SLICE;
  for (int i = t; i < EDGES_PER_SLICE; i += 256) {
    int c = ei[N_EDGES + base + i];
    int r = ei[base + i];
    float w = ew[base + i];
    int bk = c >> BSH;
    int rank = atomicAdd(&rnk[bk], 1);
    unsigned long long v = ((unsigned long long)__float_as_uint(w) << 32)
                         | ((unsigned long long)(unsigned)r << BSH)
                         | (unsigned long long)(c & 127);
    bucketed[(size_t)sbase[bk] + rank] = v;
  }
}

// ---------------- phase B: per-bucket degree + CSR build (fused, block-exclusive) ----------------
// cpack = bf16(w)<<16 | r   (dinv folded into rows / applied at aggregate)
__global__ __launch_bounds__(256) void csrB_k(const unsigned long long* __restrict__ bucketed,
                                              const int* __restrict__ boff,
                                              int* __restrict__ off, float* __restrict__ dinv,
                                              unsigned int* __restrict__ cpack) {
  __shared__ int cnt[128];
  __shared__ float wsum[128];
  __shared__ int sc[128];
  __shared__ int cnt2[128];
  int b = blockIdx.x, t = threadIdx.x;
  if (t < 128) { cnt[t] = 0; cnt2[t] = 0; wsum[t] = 1.0f; }   // self-loop weight
  __syncthreads();
  int s = boff[b], e = boff[b + 1];
  for (int i = s + t; i < e; i += 256) {
    unsigned long long v = bucketed[i];
    atomicAdd(&cnt[(int)(v & 127)], 1);
    atomicAdd(&wsum[(int)(v & 127)], __uint_as_float((unsigned)(v >> 32)));
  }
  __syncthreads();
  if (t < 128) sc[t] = cnt[t];
  __syncthreads();
  for (int d = 1; d < 128; d <<= 1) {
    int v = (t < 128 && t >= d) ? sc[t - d] : 0;
    __syncthreads();
    if (t < 128) sc[t] += v;
    __syncthreads();
  }
  int node = b * 128 + t;
  if (t < 128 && node < N_NODES) {
    off[node] = s + sc[t] - cnt[t];
    dinv[node] = rsqrtf(wsum[t]);
  }
  __syncthreads();
  for (int i = s + t; i < e; i += 256) {
    unsigned long long v = bucketed[i];
    int cl = (int)(v & 127);
    int r = (int)((v >> BSH) & 0xFFFF);
    float w = __uint_as_float((unsigned)(v >> 32));
    int rank = atomicAdd(&cnt2[cl], 1);
    int pos = s + sc[cl] - cnt[cl] + rank;
    cpack[pos] = ((unsigned int)f2b(w) << 16) | (unsigned int)r;
  }
  if (b == 0 && t == 0) off[N_NODES] = N_EDGES;
}

// ---------------- MFMA bf16 GEMM, epilogue: fp8(dinv[row] * acc) ----------------
__global__ __launch_bounds__(256) void gemm_mfma_k(const unsigned short* __restrict__ A,
                                                   const unsigned short* __restrict__ W16,
                                                   const float* __restrict__ dinv,
                                                   unsigned char* __restrict__ Out8) {
  __shared__ unsigned short Wl[128 * 128];
  int t = threadIdx.x;
  for (int idx = t; idx < 2048; idx += 256) {
    int n = idx >> 4, G = idx & 15;
    short8v v = *(const short8v*)(W16 + n * 128 + G * 8);
    int Gs = G ^ (n & 15);
    *(short8v*)(&Wl[n * 128 + Gs * 8]) = v;
  }
  __syncthreads();

  int wave = t >> 6, lane = t & 63;
  int l15 = lane & 15, l4 = lane >> 4;
  int rbase = blockIdx.x * 128 + wave * 32;

  float4v acc[2][8];
#pragma unroll
  for (int m = 0; m < 2; ++m)
#pragma unroll
    for (int f = 0; f < 8; ++f) acc[m][f] = (float4v){0.f, 0.f, 0.f, 0.f};

  int r0 = rbase + l15;        if (r0 >= N_NODES) r0 = N_NODES - 1;
  int r1 = rbase + 16 + l15;   if (r1 >= N_NODES) r1 = N_NODES - 1;

#pragma unroll
  for (int s = 0; s < 4; ++s) {
    int kk = s * 32 + l4 * 8;
    short8v a0 = *(const short8v*)(A + (size_t)r0 * 128 + kk);
    short8v a1 = *(const short8v*)(A + (size_t)r1 * 128 + kk);
#pragma unroll
    for (int f = 0; f < 8; ++f) {
      int n = f * 16 + l15;
      int G = s * 4 + l4;
      int Gs = G ^ (n & 15);
      short8v bfr = *(const short8v*)(&Wl[n * 128 + Gs * 8]);
      acc[0][f] = __builtin_amdgcn_mfma_f32_16x16x32_bf16(a0, bfr, acc[0][f], 0, 0, 0);
      acc[1][f] = __builtin_amdgcn_mfma_f32_16x16x32_bf16(a1, bfr, acc[1][f], 0, 0, 0);
    }
  }

#pragma unroll
  for (int m = 0; m < 2; ++m) {
    int rb = rbase + m * 16 + l4 * 4;
#pragma unroll
    for (int r = 0; r < 4; ++r) {
      int row = rb + r;
      if (row < N_NODES) {
        float ds = dinv[row];
        unsigned char* orow = Out8 + (size_t)row * 128 + l15;
#pragma unroll
        for (int f = 0; f < 8; ++f) orow[f * 16] = f2fp8(acc[m][f][r] * ds);
      }
    }
  }
}

// ---------------- aggregate: out[c] = elu(dinv_c*(h8[c] + sum w*h8[r]) + b) ----------------
// 16 lanes per node (8 fp8 features per lane via u64 gathers), 4 nodes per wave,
// 16 nodes per block.
__global__ __launch_bounds__(256) void aggregate_k(const unsigned char* __restrict__ h8,
                                                   const float* __restrict__ dinv,
                                                   const int* __restrict__ off,
                                                   const unsigned int* __restrict__ cpack,
                                                   const float* __restrict__ bias,
                                                   unsigned short* __restrict__ hout) {
  int c = blockIdx.x * 16 + (threadIdx.x >> 4);
  if (c >= N_NODES) return;
  int fl = threadIdx.x & 15;            // feature lane: features 8fl..8fl+7
  const uint2* h8q = (const uint2*)h8;  // 16 uint2 per row
  uint2 sv = h8q[((size_t)c << 4) + fl];
  float2v s0 = fp8x2lo(sv.x), s1 = fp8x2hi(sv.x), s2 = fp8x2lo(sv.y), s3 = fp8x2hi(sv.y);
  float a0 = s0.x, a1 = s0.y, a2 = s1.x, a3 = s1.y;
  float a4 = s2.x, a5 = s2.y, a6 = s3.x, a7 = s3.y;
  int s = off[c], e = off[c + 1];
  int k = s;
  for (; k + 8 <= e; k += 8) {
    unsigned int p0 = cpack[k],   p1 = cpack[k+1], p2 = cpack[k+2], p3 = cpack[k+3];
    unsigned int p4 = cpack[k+4], p5 = cpack[k+5], p6 = cpack[k+6], p7 = cpack[k+7];
    uint2 g0 = h8q[((size_t)(p0 & 0xFFFF) << 4) + fl];
    uint2 g1 = h8q[((size_t)(p1 & 0xFFFF) << 4) + fl];
    uint2 g2 = h8q[((size_t)(p2 & 0xFFFF) << 4) + fl];
    uint2 g3 = h8q[((size_t)(p3 & 0xFFFF) << 4) + fl];
    uint2 g4 = h8q[((size_t)(p4 & 0xFFFF) << 4) + fl];
    uint2 g5 = h8q[((size_t)(p5 & 0xFFFF) << 4) + fl];
    uint2 g6 = h8q[((size_t)(p6 & 0xFFFF) << 4) + fl];
    uint2 g7 = h8q[((size_t)(p7 & 0xFFFF) << 4) + fl];
    float w0 = bhi(p0), w1 = bhi(p1), w2 = bhi(p2), w3 = bhi(p3);
    float w4 = bhi(p4), w5 = bhi(p5), w6 = bhi(p6), w7 = bhi(p7);
#define AGG_EDGE(G, W) { \
    float2v q0 = fp8x2lo(G.x), q1 = fp8x2hi(G.x), q2 = fp8x2lo(G.y), q3 = fp8x2hi(G.y); \
    a0 += W * q0.x; a1 += W * q0.y; a2 += W * q1.x; a3 += W * q1.y; \
    a4 += W * q2.x; a5 += W * q2.y; a6 += W * q3.x; a7 += W * q3.y; }
    AGG_EDGE(g0, w0) AGG_EDGE(g1, w1) AGG_EDGE(g2, w2) AGG_EDGE(g3, w3)
    AGG_EDGE(g4, w4) AGG_EDGE(g5, w5) AGG_EDGE(g6, w6) AGG_EDGE(g7, w7)
  }
  for (; k < e; ++k) {
    unsigned int p = cpack[k];
    uint2 g = h8q[((size_t)(p & 0xFFFF) << 4) + fl];
    float w = bhi(p);
    AGG_EDGE(g, w)
  }
#undef AGG_EDGE
  float dc = dinv[c];
  int col = fl * 8;
  float4 b0 = *(const float4*)(bias + col);
  float4 b1 = *(const float4*)(bias + col + 4);
  a0 = dc * a0 + b0.x;  a1 = dc * a1 + b0.y;  a2 = dc * a2 + b0.z;  a3 = dc * a3 + b0.w;
  a4 = dc * a4 + b1.x;  a5 = dc * a5 + b1.y;  a6 = dc * a6 + b1.z;  a7 = dc * a7 + b1.w;
  a0 = a0 > 0.f ? a0 : expm1f(a0);
  a1 = a1 > 0.f ? a1 : expm1f(a1);
  a2 = a2 > 0.f ? a2 : expm1f(a2);
  a3 = a3 > 0.f ? a3 : expm1f(a3);
  a4 = a4 > 0.f ? a4 : expm1f(a4);
  a5 = a5 > 0.f ? a5 : expm1f(a5);
  a6 = a6 > 0.f ? a6 : expm1f(a6);
  a7 = a7 > 0.f ? a7 : expm1f(a7);
  short8v o;
  o[0] = (short)f2b(a0); o[1] = (short)f2b(a1); o[2] = (short)f2b(a2); o[3] = (short)f2b(a3);
  o[4] = (short)f2b(a4); o[5] = (short)f2b(a5); o[6] = (short)f2b(a6); o[7] = (short)f2b(a7);
  *(short8v*)(hout + (size_t)c * 128 + col) = o;
}

// ---------------- fused mean-pool + head: 512 thr = 8 node-groups x 64 lanes ----------------
__global__ __launch_bounds__(512) void poolhead_k(const unsigned short* __restrict__ h,
                                                  const int* __restrict__ batch,
                                                  const float* __restrict__ fc1w, const float* __restrict__ fc1b,
                                                  const float* __restrict__ fc2w, const float* __restrict__ fc2b,
                                                  float* __restrict__ out) {
  __shared__ float part[8][HDIM];
  __shared__ float ps[HDIM];
  __shared__ float z1[HDIM];
  __shared__ float z2[NCLS];
  int g = blockIdx.x, t = threadIdx.x;
  int fl = t & 63;            // u32 word: features 2fl, 2fl+1
  int grp = t >> 6;           // 0..7
  int lo = 0, hi = N_NODES;
  while (lo < hi) { int mid = (lo + hi) >> 1; if (batch[mid] < g) lo = mid + 1; else hi = mid; }
  int gs = lo;
  hi = N_NODES;
  while (lo < hi) { int mid = (lo + hi) >> 1; if (batch[mid] < g + 1) lo = mid + 1; else hi = mid; }
  int ge = lo;
  const unsigned int* hw = (const unsigned int*)h;   // 64 u32 per row
  float a0 = 0.f, a1 = 0.f;
  for (int n = gs + grp; n < ge; n += 8) {
    unsigned int v = hw[((size_t)n << 6) + fl];
    a0 += blo(v); a1 += bhi(v);
  }
  part[grp][fl * 2] = a0;
  part[grp][fl * 2 + 1] = a1;
  __syncthreads();
  if (t < HDIM) {
    float s = 0.f;
#pragma unroll
    for (int q = 0; q < 8; ++q) s += part[q][t];
    ps[t] = s / (float)max(ge - gs, 1);
  }
  __syncthreads();
  if (t < HDIM) {
    float acc = fc1b[t];
    for (int i = 0; i < HDIM; ++i) acc += ps[i] * fc1w[t * HDIM + i];
    z1[t] = (acc > 0.f) ? acc : expm1f(acc);
  }
  __syncthreads();
  if (t < NCLS) {
    float a2 = fc2b[t];
    for (int i = 0; i < HDIM; ++i) a2 += z1[i] * fc2w[t * HDIM + i];
    z2[t] = a2;
  }
  __syncthreads();
  if (t == 0) {
    float m = -1e30f;
    for (int i = 0; i < NCLS; ++i) m = fmaxf(m, z2[i]);
    float s2 = 0.f;
    for (int i = 0; i < NCLS; ++i) s2 += expf(z2[i] - m);
    float l = logf(s2);
    for (int i = 0; i < NCLS; ++i) out[g * NCLS + i] = z2[i] - m - l;
  }
}

// ---------------- launch ----------------
static inline size_t align256(size_t x) { return (x + 255) & ~(size_t)255; }

extern "C" void kernel_launch(void* const* d_in, const int* in_sizes, int n_in,
                              void* d_out, int out_size, void* d_ws, size_t ws_size,
                              hipStream_t stream) {
  const float* x     = (const float*)d_in[0];
  const int*   ei    = (const int*)d_in[1];
  const float* ew    = (const float*)d_in[2];
  const int*   batch = (const int*)d_in[3];
  const float* Wl[4] = { (const float*)d_in[4], (const float*)d_in[6], (const float*)d_in[8], (const float*)d_in[10] };
  const float* bl[4] = { (const float*)d_in[5], (const float*)d_in[7], (const float*)d_in[9], (const float*)d_in[11] };
  const float* fc1w = (const float*)d_in[12];
  const float* fc1b = (const float*)d_in[13];
  const float* fc2w = (const float*)d_in[14];
  const float* fc2b = (const float*)d_in[15];
  float* out = (float*)d_out;

  char* ws = (char*)d_ws;
  size_t o = 0;
  unsigned short* x16 = (unsigned short*)(ws + o); o = align256(o + (size_t)N_NODES * HDIM * 2);
  unsigned short* h16 = (unsigned short*)(ws + o); o = align256(o + (size_t)N_NODES * HDIM * 2);
  // h8 (6.4MB) aliases bucketed (12.8MB): bucketed dead after csrB_k; h8 first
  // written by gemm_mfma_k (launched after csrB_k).
  unsigned char* h8 = (unsigned char*)(ws + o);
  unsigned long long* bucketed = (unsigned long long*)(ws + o);
  o = align256(o + (size_t)N_EDGES * 8);
  unsigned short* w16[4];
  for (int l = 0; l < 4; ++l) { w16[l] = (unsigned short*)(ws + o); o = align256(o + (size_t)HDIM * HDIM * 2); }
  unsigned int* cpack = (unsigned int*)(ws + o); o = align256(o + (size_t)N_EDGES * 4);
  int*   partialB = (int*)(ws + o);   o = align256(o + (size_t)NSLICE * NBUCK * 4);
  int*   boff     = (int*)(ws + o);   o = align256(o + (size_t)(NBUCK + 1) * 4);
  float* dinv  = (float*)(ws + o); o = align256(o + (size_t)N_NODES * 4);
  int*   off   = (int*)  (ws + o); o = align256(o + (size_t)(N_NODES + 1) * 4);

  cast4_k<<<(N_NODES * HDIM / 4 + 255) / 256, 256, 0, stream>>>(x, x16, N_NODES * HDIM / 4);
  castw_k<<<64, 256, 0, stream>>>(Wl[0], Wl[1], Wl[2], Wl[3], w16[0], w16[1], w16[2], w16[3]);

  countA_k<<<NSLICE, 256, 0, stream>>>(ei, partialB);
  prefixA1_k<<<(NBUCK + 255) / 256, 256, 0, stream>>>(partialB, boff);
  prefixA2_k<<<1, 512, 0, stream>>>(boff);
  bucketA_k<<<NSLICE, 256, 0, stream>>>(ei, ew, partialB, boff, bucketed);
  csrB_k<<<NBUCK, 256, 0, stream>>>(bucketed, boff, off, dinv, cpack);

  const unsigned short* hin = x16;
  for (int l = 0; l < 4; ++l) {
    gemm_mfma_k<<<(N_NODES + 127) / 128, 256, 0, stream>>>(hin, w16[l], dinv, h8);
    aggregate_k<<<(N_NODES + 15) / 16, 256, 0, stream>>>(h8, dinv, off, cpack, bl[l], h16);
    hin = h16;
  }

  poolhead_k<<<NGRAPH, 512, 0, stream>>>(h16, batch, fc1w, fc1b, fc2w, fc2b, out);
}